// Round 9
// baseline (257.533 us; speedup 1.0000x reference)
//
#include <hip/hip_runtime.h>
#include <stdint.h>

// ---------------------------------------------------------------------------
// WideAndDeep: B=16384, F=3, C=256, D=64, H=1024, ND=13
// Two-kernel pipeline:
//  mega1: [0,512)  GEMM1 128x256 tile, staging built in-kernel from
//                  emb/sp/dense (A) and f32 W1 (B) — no intermediates;
//         [512,768) W2 -> bf16; [768,800) wide path + b3 seed + cnt=0.
//  gemm2: R7-structure GEMM (128x256, BK=32 dbuf, 2 blocks/CU) fusing the
//         W3 matvec via atomicAdd into wide, plus last-block sigmoid tail.
// ---------------------------------------------------------------------------

#define BATCH 16384
#define HDIM 1024
#define K1 224
#define DEEP_IN 205

typedef short bf16x8 __attribute__((ext_vector_type(8)));
typedef float f32x4 __attribute__((ext_vector_type(4)));
typedef uint16_t u16x8 __attribute__((ext_vector_type(8)));

__device__ __forceinline__ uint16_t f2bf(float f) {
    uint32_t x;
    __builtin_memcpy(&x, &f, 4);
    uint32_t r = (x + 0x7fffu + ((x >> 16) & 1u)) >> 16;
    return (uint16_t)r;
}

__device__ __forceinline__ void async_ld16(const uint16_t* g, uint16_t* l) {
    __builtin_amdgcn_global_load_lds(
        (const __attribute__((address_space(1))) uint32_t*)g,
        (__attribute__((address_space(3))) uint32_t*)l, 16, 0, 0);
}

// ---------------------------------------------------------------------------
// mega1
// ---------------------------------------------------------------------------
__global__ __launch_bounds__(512, 4) void mega1(
    const int* __restrict__ sp, const float* __restrict__ dense,
    const float* __restrict__ emb, const float* __restrict__ W1,
    const float* __restrict__ b1, const float* __restrict__ W2,
    const float* __restrict__ ww, const float* __restrict__ wb,
    const float* __restrict__ b3,
    uint16_t* __restrict__ h1, uint16_t* __restrict__ W2b,
    float* __restrict__ wide, unsigned* __restrict__ cnt)
{
    const int bid = blockIdx.x;
    const int tid = threadIdx.x;

    if (bid >= 512) {
        if (bid < 768) {                   // ---- W2 convert (f32 -> bf16 x8)
            int k = (bid - 512) * 512 + tid;   // < 131072
            const float* src = W2 + (size_t)k * 8;
            float4 v0 = *(const float4*)src;
            float4 v1 = *(const float4*)(src + 4);
            u16x8 o;
            o[0] = f2bf(v0.x); o[1] = f2bf(v0.y); o[2] = f2bf(v0.z); o[3] = f2bf(v0.w);
            o[4] = f2bf(v1.x); o[5] = f2bf(v1.y); o[6] = f2bf(v1.z); o[7] = f2bf(v1.w);
            *(u16x8*)(W2b + (size_t)k * 8) = o;
        } else {                           // ---- wide path (+ b3 seed)
            int b = (bid - 768) * 512 + tid;   // < 16384
            int s0 = sp[b * 3], s1 = sp[b * 3 + 1], s2 = sp[b * 3 + 2];
            float w = wb[0] + b3[0];
            w += ww[s0] + ww[256 + s1] + ww[512 + s2];
            w += ww[768    + s0 * 3 + s1];
            w += ww[66304  + s0 * 3 + s2];
            w += ww[131840 + s1 * 3 + s2];
            w += ww[197376 + (s0 * 3 + s1) * 3 + s2];
            const float* wd = ww + 16974592;
            float acc = 0.f;
#pragma unroll
            for (int j = 0; j < 13; j++) acc += dense[b * 13 + j] * wd[j];
            wide[b] = w + acc;
            if (bid == 768 && tid == 0) *cnt = 0u;
        }
        return;
    }

    // ---- GEMM1: h1 = relu(deep_x @ W1^T + b1), deep_x built on the fly.
    __shared__ __align__(16) uint16_t Al[4096];   // 128 x 32, fragment order
    __shared__ __align__(16) uint16_t Bl[8192];   // 256 x 32

    const int lane = tid & 63;
    const int wave = tid >> 6;    // 0..7
    const int wm = wave >> 2;     // 0..1
    const int wn = wave & 3;      // 0..3
    const int xcd = bid & 7;
    const int slot = bid >> 3;
    const int by = xcd * 16 + (slot >> 2);   // M=16384 -> 128 m-bands, 16/XCD
    const int bx = slot & 3;
    const int bm = by * 128;
    const int bn = bx * 256;
    const int rl = lane & 15, q = lane >> 4;

    // A source: lane builds row rA of chunk `wave`, k-span x = k0 + q*8.
    const int rA = bm + wave * 16 + rl;
    const int s0 = sp[rA * 3], s1 = sp[rA * 3 + 1], s2 = sp[rA * 3 + 2];
    const float* e0 = emb + (size_t)s0 * 64;
    const float* e1 = emb + (size_t)(256 + s1) * 64;
    const float* e2 = emb + (size_t)(512 + s2) * 64;
    const float* dA = dense + (size_t)rA * 13;
    // B source: lane builds rows n0 (chunk 2w), n1 (chunk 2w+1) of W1.
    const int n0 = bn + (2 * wave) * 16 + rl;
    const float* w10 = W1 + (size_t)n0 * 205;
    const float* w11 = w10 + (size_t)16 * 205;

    f32x4 acc[4][4];
#pragma unroll
    for (int i = 0; i < 4; i++)
#pragma unroll
        for (int j = 0; j < 4; j++) acc[i][j] = (f32x4)0.f;

    u16x8 a8, bb0, bb1;

#define BUILD(K0)                                                              \
    {                                                                          \
        int x = (K0) + q * 8;                                                  \
        if (x < 192) {                                                         \
            const float* e = (x < 64) ? (e0 + x)                               \
                           : (x < 128) ? (e1 + (x - 64)) : (e2 + (x - 128));   \
            float4 v0 = *(const float4*)e;                                     \
            float4 v1 = *(const float4*)(e + 4);                               \
            a8[0] = f2bf(v0.x); a8[1] = f2bf(v0.y);                            \
            a8[2] = f2bf(v0.z); a8[3] = f2bf(v0.w);                            \
            a8[4] = f2bf(v1.x); a8[5] = f2bf(v1.y);                            \
            a8[6] = f2bf(v1.z); a8[7] = f2bf(v1.w);                            \
        } else {                                                               \
            _Pragma("unroll") for (int t = 0; t < 8; t++) {                    \
                int c = x + t;                                                 \
                a8[t] = (c < DEEP_IN) ? f2bf(dA[c - 192]) : (uint16_t)0;       \
            }                                                                  \
        }                                                                      \
        _Pragma("unroll") for (int t = 0; t < 8; t++) {                        \
            int c = x + t;                                                     \
            bb0[t] = (c < DEEP_IN) ? f2bf(w10[c]) : (uint16_t)0;               \
            bb1[t] = (c < DEEP_IN) ? f2bf(w11[c]) : (uint16_t)0;               \
        }                                                                      \
    }

    BUILD(0)
    for (int k0 = 0; k0 < K1; k0 += 32) {
        __syncthreads();   // previous compute done; LDS safe to overwrite
        *(u16x8*)&Al[wave * 512 + lane * 8] = a8;
        *(u16x8*)&Bl[(2 * wave) * 512 + lane * 8] = bb0;
        *(u16x8*)&Bl[(2 * wave + 1) * 512 + lane * 8] = bb1;
        __syncthreads();
        if (k0 + 32 < K1) BUILD(k0 + 32)   // prefetch next (overlaps MFMA)
        bf16x8 af[4], bfr[4];
#pragma unroll
        for (int i = 0; i < 4; i++)
            af[i] = *(const bf16x8*)&Al[(wm * 4 + i) * 512 + lane * 8];
#pragma unroll
        for (int j = 0; j < 4; j++)
            bfr[j] = *(const bf16x8*)&Bl[(wn * 4 + j) * 512 + lane * 8];
#pragma unroll
        for (int i = 0; i < 4; i++)
#pragma unroll
            for (int j = 0; j < 4; j++)
                acc[i][j] = __builtin_amdgcn_mfma_f32_16x16x32_bf16(
                    af[i], bfr[j], acc[i][j], 0, 0, 0);
    }
#undef BUILD

    // Epilogue: C/D layout col = lane&15, row = (lane>>4)*4 + reg
#pragma unroll
    for (int i = 0; i < 4; i++) {
#pragma unroll
        for (int j = 0; j < 4; j++) {
            int n = bn + (wn * 4 + j) * 16 + rl;
            float bv = b1[n];
#pragma unroll
            for (int r = 0; r < 4; r++) {
                int m = bm + (wm * 4 + i) * 16 + q * 4 + r;
                h1[(size_t)m * HDIM + n] = f2bf(fmaxf(acc[i][j][r] + bv, 0.f));
            }
        }
    }
}

// ---------------------------------------------------------------------------
// gemm2: h2-free GEMM2 (R7 core) + W3 matvec fusion + last-block sigmoid.
// ---------------------------------------------------------------------------
__global__ __launch_bounds__(512, 4) void gemm2(
    const uint16_t* __restrict__ A, const uint16_t* __restrict__ Bw,
    const float* __restrict__ bias, const float* __restrict__ W3,
    float* __restrict__ outacc, float* __restrict__ out,
    unsigned* __restrict__ cnt)
{
    __shared__ __align__(16) uint16_t Al[2][4096];   // 128 x 32 dbuf
    __shared__ __align__(16) uint16_t Bl[2][8192];   // 256 x 32 dbuf

    const int tid = threadIdx.x;
    const int lane = tid & 63;
    const int wave = tid >> 6;
    const int wm = wave >> 2;
    const int wn = wave & 3;
    const int id = blockIdx.x;
    const int xcd = id & 7;
    const int slot = id >> 3;
    const int by = xcd * 16 + (slot >> 2);
    const int bx = slot & 3;
    const int bm = by * 128;
    const int bn = bx * 256;
    const int rl = lane & 15, q = lane >> 4;
    const int K = HDIM;

    f32x4 acc[4][4];
#pragma unroll
    for (int i = 0; i < 4; i++)
#pragma unroll
        for (int j = 0; j < 4; j++) acc[i][j] = (f32x4)0.f;

    const uint16_t* aS = A + (size_t)(bm + wave * 16 + rl) * K + q * 8;
    const uint16_t* bS0 = Bw + (size_t)(bn + wave * 32 + rl) * K + q * 8;
    const uint16_t* bS1 = bS0 + (size_t)16 * K;
    const int dA = wave * 512, dB0 = wave * 1024, dB1 = wave * 1024 + 512;

    async_ld16(aS, &Al[0][dA]);
    async_ld16(bS0, &Bl[0][dB0]);
    async_ld16(bS1, &Bl[0][dB1]);
    asm volatile("s_waitcnt vmcnt(0)" ::: "memory");
    __syncthreads();

    int p = 0;
    for (int k0 = 32; k0 < K; k0 += 32) {
        async_ld16(aS + k0, &Al[p ^ 1][dA]);
        async_ld16(bS0 + k0, &Bl[p ^ 1][dB0]);
        async_ld16(bS1 + k0, &Bl[p ^ 1][dB1]);

        bf16x8 af[4], bfr[4];
#pragma unroll
        for (int i = 0; i < 4; i++)
            af[i] = *(const bf16x8*)&Al[p][(wm * 4 + i) * 512 + lane * 8];
#pragma unroll
        for (int j = 0; j < 4; j++)
            bfr[j] = *(const bf16x8*)&Bl[p][(wn * 4 + j) * 512 + lane * 8];
#pragma unroll
        for (int i = 0; i < 4; i++)
#pragma unroll
            for (int j = 0; j < 4; j++)
                acc[i][j] = __builtin_amdgcn_mfma_f32_16x16x32_bf16(
                    af[i], bfr[j], acc[i][j], 0, 0, 0);

        asm volatile("s_waitcnt vmcnt(0)" ::: "memory");
        __syncthreads();
        p ^= 1;
    }
    {
        bf16x8 af[4], bfr[4];
#pragma unroll
        for (int i = 0; i < 4; i++)
            af[i] = *(const bf16x8*)&Al[p][(wm * 4 + i) * 512 + lane * 8];
#pragma unroll
        for (int j = 0; j < 4; j++)
            bfr[j] = *(const bf16x8*)&Bl[p][(wn * 4 + j) * 512 + lane * 8];
#pragma unroll
        for (int i = 0; i < 4; i++)
#pragma unroll
            for (int j = 0; j < 4; j++)
                acc[i][j] = __builtin_amdgcn_mfma_f32_16x16x32_bf16(
                    af[i], bfr[j], acc[i][j], 0, 0, 0);
    }

    // Epilogue: fold relu(acc + b2) . W3 per row, atomicAdd into outacc.
    float bv[4], w3v[4];
#pragma unroll
    for (int j = 0; j < 4; j++) {
        int n = bn + (wn * 4 + j) * 16 + rl;
        bv[j] = bias[n];
        w3v[j] = W3[n];
    }
#pragma unroll
    for (int i = 0; i < 4; i++) {
#pragma unroll
        for (int r = 0; r < 4; r++) {
            float pt = 0.f;
#pragma unroll
            for (int j = 0; j < 4; j++)
                pt += fmaxf(acc[i][j][r] + bv[j], 0.f) * w3v[j];
            pt += __shfl_xor(pt, 1);
            pt += __shfl_xor(pt, 2);
            pt += __shfl_xor(pt, 4);
            pt += __shfl_xor(pt, 8);
            if (rl == 0) {
                int m = bm + (wm * 4 + i) * 16 + q * 4 + r;
                atomicAdd(&outacc[m], pt);
            }
        }
    }

    // Last-block sigmoid tail (device-scope counter; no spinning).
    __threadfence();
    __syncthreads();
    __shared__ unsigned lastv;
    if (tid == 0) {
        lastv = __hip_atomic_fetch_add(cnt, 1u, __ATOMIC_ACQ_REL,
                                       __HIP_MEMORY_SCOPE_AGENT);
    }
    __syncthreads();
    if (lastv == 511u) {
        for (int i2 = tid; i2 < BATCH; i2 += 512) {
            float v = __hip_atomic_load(&outacc[i2], __ATOMIC_RELAXED,
                                        __HIP_MEMORY_SCOPE_AGENT);
            out[i2] = 1.f / (1.f + __expf(-v));
        }
    }
}

// ---------------------------------------------------------------------------
extern "C" void kernel_launch(void* const* d_in, const int* in_sizes, int n_in,
                              void* d_out, int out_size, void* d_ws, size_t ws_size,
                              hipStream_t stream) {
    const int*   sp    = (const int*)d_in[0];
    const float* dense = (const float*)d_in[1];
    const float* ww    = (const float*)d_in[2];
    const float* wb    = (const float*)d_in[3];
    const float* emb   = (const float*)d_in[4];
    const float* W1    = (const float*)d_in[5];
    const float* b1    = (const float*)d_in[6];
    const float* W2    = (const float*)d_in[7];
    const float* b2    = (const float*)d_in[8];
    const float* W3    = (const float*)d_in[9];
    const float* b3    = (const float*)d_in[10];
    float* out = (float*)d_out;

    char* ws = (char*)d_ws;
    unsigned* cnt  = (unsigned*)ws;                    // 4 B (pad to 4096)
    float*    wide = (float*)(ws + 4096);              // 65,536 B
    uint16_t* W2b  = (uint16_t*)(ws + 69632);          // 2,097,152 B
    uint16_t* h1   = (uint16_t*)(ws + 2166784);        // 33,554,432 B -> 35.7 MB

    mega1<<<800, 512, 0, stream>>>(sp, dense, emb, W1, b1, W2, ww, wb, b3,
                                   h1, W2b, wide, cnt);
    gemm2<<<512, 512, 0, stream>>>(h1, W2b, b2, W3, wide, out, cnt);
}

// Round 10
// 226.377 us; speedup vs baseline: 1.1376x; 1.1376x over previous
//
#include <hip/hip_runtime.h>
#include <stdint.h>

// ---------------------------------------------------------------------------
// WideAndDeep: B=16384, F=3, C=256, D=64, H=1024, ND=13
// deep_in = 205 padded to 256.
// gemm_relu (GEMM1): R7 dbuf core, 128x256 tile, BK=32.
// gemm_fused (GEMM2): NEW core — B-only LDS staging (A-fragments loaded
// straight from global to VGPRs; 4-way dup served by L1/L2), BK=64, single
// s_barrier per iter, staging waits have one full iteration of slack.
// W3 matvec fused via atomicAdd. NO device-scope fences anywhere (R8 lesson).
// ---------------------------------------------------------------------------

#define BATCH 16384
#define HDIM 1024
#define KPAD 256
#define DEEP_IN 205

typedef short bf16x8 __attribute__((ext_vector_type(8)));
typedef float f32x4 __attribute__((ext_vector_type(4)));
typedef uint16_t u16x8 __attribute__((ext_vector_type(8)));

__device__ __forceinline__ uint16_t f2bf(float f) {
    uint32_t x;
    __builtin_memcpy(&x, &f, 4);
    uint32_t r = (x + 0x7fffu + ((x >> 16) & 1u)) >> 16;
    return (uint16_t)r;
}

__device__ __forceinline__ void async_ld16(const uint16_t* g, uint16_t* l) {
    __builtin_amdgcn_global_load_lds(
        (const __attribute__((address_space(1))) uint32_t*)g,
        (__attribute__((address_space(3))) uint32_t*)l, 16, 0, 0);
}

// ---------------------------------------------------------------------------
// Fused prep:
//   blocks [0, 2048)      : build deep_x  [B][256] bf16  (x8 vectorized)
//   blocks [2048, 2560)   : W2 -> bf16               (x8 vectorized)
//   blocks [2560, 2688)   : W1 -> bf16 K-padded      (x8 vectorized)
//   blocks [2688, 2752)   : wide path + b3 seed (atomicAdd target for GEMM2)
// ---------------------------------------------------------------------------
__global__ __launch_bounds__(256) void prep_kernel(
    const int* __restrict__ sp, const float* __restrict__ dense,
    const float* __restrict__ emb,
    const float* __restrict__ W1, const float* __restrict__ W2,
    const float* __restrict__ ww, const float* __restrict__ wb,
    const float* __restrict__ b3,
    uint16_t* __restrict__ dx, uint16_t* __restrict__ W1b,
    uint16_t* __restrict__ W2b, float* __restrict__ wide)
{
    const int bid = blockIdx.x;
    if (bid < 2048) {                      // ---- deep_x build
        int idx = bid * 256 + threadIdx.x; // < 16384*32
        int b = idx >> 5, c0 = (idx & 31) * 8;
        u16x8 o;
        if (c0 < 192) {
            int f = c0 >> 6, cc = c0 & 63;
            int s = sp[b * 3 + f];
            const float* e = emb + (size_t)(((f << 8) + s) * 64 + cc);
            float4 v0 = *(const float4*)e;
            float4 v1 = *(const float4*)(e + 4);
            o[0] = f2bf(v0.x); o[1] = f2bf(v0.y); o[2] = f2bf(v0.z); o[3] = f2bf(v0.w);
            o[4] = f2bf(v1.x); o[5] = f2bf(v1.y); o[6] = f2bf(v1.z); o[7] = f2bf(v1.w);
        } else {
#pragma unroll
            for (int t = 0; t < 8; t++) {
                int c = c0 + t;
                o[t] = (c >= 192 && c < DEEP_IN) ? f2bf(dense[b * 13 + (c - 192)])
                                                 : (uint16_t)0;
            }
        }
        *(u16x8*)(dx + (size_t)idx * 8) = o;
    } else if (bid < 2560) {               // ---- W2 convert
        int k = (bid - 2048) * 256 + threadIdx.x;  // < 131072
        const float* src = W2 + (size_t)k * 8;
        float4 v0 = *(const float4*)src;
        float4 v1 = *(const float4*)(src + 4);
        u16x8 o;
        o[0] = f2bf(v0.x); o[1] = f2bf(v0.y); o[2] = f2bf(v0.z); o[3] = f2bf(v0.w);
        o[4] = f2bf(v1.x); o[5] = f2bf(v1.y); o[6] = f2bf(v1.z); o[7] = f2bf(v1.w);
        *(u16x8*)(W2b + (size_t)k * 8) = o;
    } else if (bid < 2688) {               // ---- W1 convert, pad 205->256
        int idx = (bid - 2560) * 256 + threadIdx.x;  // < 32768
        int n = idx >> 5, c0 = (idx & 31) * 8;
        u16x8 o;
#pragma unroll
        for (int t = 0; t < 8; t++) {
            int c = c0 + t;
            o[t] = (c < DEEP_IN) ? f2bf(W1[n * DEEP_IN + c]) : (uint16_t)0;
        }
        *(u16x8*)(W1b + (size_t)idx * 8) = o;
    } else {                               // ---- wide path (+ b3 seed)
        int b = (bid - 2688) * 256 + threadIdx.x;  // < 16384
        int s0 = sp[b * 3], s1 = sp[b * 3 + 1], s2 = sp[b * 3 + 2];
        float w = wb[0] + b3[0];
        w += ww[s0] + ww[256 + s1] + ww[512 + s2];
        w += ww[768    + s0 * 3 + s1];
        w += ww[66304  + s0 * 3 + s2];
        w += ww[131840 + s1 * 3 + s2];
        w += ww[197376 + (s0 * 3 + s1) * 3 + s2];
        const float* wd = ww + 16974592;
        float acc = 0.f;
#pragma unroll
        for (int j = 0; j < 13; j++) acc += dense[b * 13 + j] * wd[j];
        wide[b] = w + acc;
    }
}

// ---------------------------------------------------------------------------
// GEMM1: C = relu(A @ Bw^T + bias) bf16. R7 dbuf core (best measured).
// 128x256 tile, 8 waves (2m x 4n), wave tile 64x64, BK=32, 2-buffer LDS.
// ---------------------------------------------------------------------------
__global__ __launch_bounds__(512, 4) void gemm_relu(
    const uint16_t* __restrict__ A, const uint16_t* __restrict__ Bw,
    const float* __restrict__ bias, uint16_t* __restrict__ C,
    int M, int N, int K)
{
    __shared__ __align__(16) uint16_t Al[2][4096];   // 128 x 32 dbuf
    __shared__ __align__(16) uint16_t Bl[2][8192];   // 256 x 32 dbuf

    const int tid = threadIdx.x;
    const int lane = tid & 63;
    const int wave = tid >> 6;
    const int wm = wave >> 2;
    const int wn = wave & 3;
    const int id = blockIdx.x;
    const int xcd = id & 7;
    const int slot = id >> 3;
    const int mbX = (M >> 7) >> 3;
    const int by = xcd * mbX + (slot >> 2);
    const int bx = slot & 3;
    const int bm = by * 128;
    const int bn = bx * 256;
    const int rl = lane & 15, q = lane >> 4;

    f32x4 acc[4][4];
#pragma unroll
    for (int i = 0; i < 4; i++)
#pragma unroll
        for (int j = 0; j < 4; j++) acc[i][j] = (f32x4)0.f;

    const uint16_t* aS = A + (size_t)(bm + wave * 16 + rl) * K + q * 8;
    const uint16_t* bS0 = Bw + (size_t)(bn + wave * 32 + rl) * K + q * 8;
    const uint16_t* bS1 = bS0 + (size_t)16 * K;
    const int dA = wave * 512, dB0 = wave * 1024, dB1 = wave * 1024 + 512;

    async_ld16(aS, &Al[0][dA]);
    async_ld16(bS0, &Bl[0][dB0]);
    async_ld16(bS1, &Bl[0][dB1]);
    asm volatile("s_waitcnt vmcnt(0)" ::: "memory");
    __syncthreads();

    int p = 0;
    for (int k0 = 32; k0 < K; k0 += 32) {
        async_ld16(aS + k0, &Al[p ^ 1][dA]);
        async_ld16(bS0 + k0, &Bl[p ^ 1][dB0]);
        async_ld16(bS1 + k0, &Bl[p ^ 1][dB1]);

        bf16x8 af[4], bfr[4];
#pragma unroll
        for (int i = 0; i < 4; i++)
            af[i] = *(const bf16x8*)&Al[p][(wm * 4 + i) * 512 + lane * 8];
#pragma unroll
        for (int j = 0; j < 4; j++)
            bfr[j] = *(const bf16x8*)&Bl[p][(wn * 4 + j) * 512 + lane * 8];
#pragma unroll
        for (int i = 0; i < 4; i++)
#pragma unroll
            for (int j = 0; j < 4; j++)
                acc[i][j] = __builtin_amdgcn_mfma_f32_16x16x32_bf16(
                    af[i], bfr[j], acc[i][j], 0, 0, 0);

        asm volatile("s_waitcnt vmcnt(0)" ::: "memory");
        __syncthreads();
        p ^= 1;
    }
    {
        bf16x8 af[4], bfr[4];
#pragma unroll
        for (int i = 0; i < 4; i++)
            af[i] = *(const bf16x8*)&Al[p][(wm * 4 + i) * 512 + lane * 8];
#pragma unroll
        for (int j = 0; j < 4; j++)
            bfr[j] = *(const bf16x8*)&Bl[p][(wn * 4 + j) * 512 + lane * 8];
#pragma unroll
        for (int i = 0; i < 4; i++)
#pragma unroll
            for (int j = 0; j < 4; j++)
                acc[i][j] = __builtin_amdgcn_mfma_f32_16x16x32_bf16(
                    af[i], bfr[j], acc[i][j], 0, 0, 0);
    }

#pragma unroll
    for (int i = 0; i < 4; i++) {
#pragma unroll
        for (int j = 0; j < 4; j++) {
            int n = bn + (wn * 4 + j) * 16 + rl;
            float bv = bias[n];
#pragma unroll
            for (int r = 0; r < 4; r++) {
                int m = bm + (wm * 4 + i) * 16 + q * 4 + r;
                float v = fmaxf(acc[i][j][r] + bv, 0.f);
                C[(size_t)m * N + n] = f2bf(v);
            }
        }
    }
}

// ---------------------------------------------------------------------------
// GEMM2 fused: NEW core. B-only LDS (2 x 32 KB, BK=64), A-fragments loaded
// global->VGPR (lane-linear dwordx4; 4-way dup via L1/L2). One s_barrier per
// iter; the vmcnt(0) drains B-staging issued a FULL iteration earlier.
// Safety: each wave waits its own staging before the barrier, so after the
// barrier all of B(k) is in LDS; B(k+1) overwrites the buffer consumed at
// iter k-1, which all waves finished before passing this barrier.
// Epilogue folds relu(acc+b2).W3 per row -> atomicAdd into outacc.
// ---------------------------------------------------------------------------
__global__ __launch_bounds__(512, 4) void gemm_fused(
    const uint16_t* __restrict__ A, const uint16_t* __restrict__ Bw,
    const float* __restrict__ bias, const float* __restrict__ W3,
    float* __restrict__ outacc, int M, int N, int K)
{
    __shared__ __align__(16) uint16_t Bl[2][16384];  // 2 x (256 rows x 64 k)

    const int tid = threadIdx.x;
    const int lane = tid & 63;
    const int wave = tid >> 6;
    const int wm = wave >> 2;
    const int wn = wave & 3;
    const int id = blockIdx.x;
    const int xcd = id & 7;
    const int slot = id >> 3;
    const int mbX = (M >> 7) >> 3;
    const int by = xcd * mbX + (slot >> 2);
    const int bx = slot & 3;
    const int bm = by * 128;
    const int bn = bx * 256;
    const int rl = lane & 15, q = lane >> 4;

    f32x4 acc[4][4];
#pragma unroll
    for (int i = 0; i < 4; i++)
#pragma unroll
        for (int j = 0; j < 4; j++) acc[i][j] = (f32x4)0.f;

    // B staging: wave stages row-chunks 2w, 2w+1 (16 rows x 64 k each = 2
    // k-half sub-chunks). LDS element base: chunk c, kh h -> c*1024 + h*512.
    const uint16_t* bS0 = Bw + (size_t)(bn + wave * 32 + rl) * K + q * 8;
    const uint16_t* bS1 = bS0 + (size_t)16 * K;
    const int dB0 = (2 * wave) * 1024, dB1 = (2 * wave + 1) * 1024;
    // A fragment base: rows bm + wm*64 + i*16 + rl, k offset q*8.
    const uint16_t* aP = A + (size_t)(bm + wm * 64 + rl) * K + q * 8;
    const size_t rs16 = (size_t)16 * K;

    // Prologue: B(0) -> buffer 0.
    async_ld16(bS0,      &Bl[0][dB0]);
    async_ld16(bS0 + 32, &Bl[0][dB0 + 512]);
    async_ld16(bS1,      &Bl[0][dB1]);
    async_ld16(bS1 + 32, &Bl[0][dB1 + 512]);

    const int niter = K >> 6;  // 16
    for (int k = 0; k < niter; ++k) {
        asm volatile("s_waitcnt vmcnt(0)" ::: "memory");  // own B(k) landed
        asm volatile("s_barrier" ::: "memory");           // all B(k) in LDS
        const int p = k & 1;
        if (k + 1 < niter) {
            const int ko = (k + 1) << 6;
            async_ld16(bS0 + ko,      &Bl[p ^ 1][dB0]);
            async_ld16(bS0 + ko + 32, &Bl[p ^ 1][dB0 + 512]);
            async_ld16(bS1 + ko,      &Bl[p ^ 1][dB1]);
            async_ld16(bS1 + ko + 32, &Bl[p ^ 1][dB1 + 512]);
        }
        const int ka = k << 6;
        // kh = 0
        {
            bf16x8 af[4], bfr[4];
#pragma unroll
            for (int i = 0; i < 4; i++)
                af[i] = *(const bf16x8*)(aP + (size_t)i * rs16 + ka);
#pragma unroll
            for (int j = 0; j < 4; j++)
                bfr[j] = *(const bf16x8*)&Bl[p][(wn * 4 + j) * 1024 + lane * 8];
#pragma unroll
            for (int i = 0; i < 4; i++)
#pragma unroll
                for (int j = 0; j < 4; j++)
                    acc[i][j] = __builtin_amdgcn_mfma_f32_16x16x32_bf16(
                        af[i], bfr[j], acc[i][j], 0, 0, 0);
        }
        // kh = 1
        {
            bf16x8 af[4], bfr[4];
#pragma unroll
            for (int i = 0; i < 4; i++)
                af[i] = *(const bf16x8*)(aP + (size_t)i * rs16 + ka + 32);
#pragma unroll
            for (int j = 0; j < 4; j++)
                bfr[j] = *(const bf16x8*)&Bl[p][(wn * 4 + j) * 1024 + 512 + lane * 8];
#pragma unroll
            for (int i = 0; i < 4; i++)
#pragma unroll
                for (int j = 0; j < 4; j++)
                    acc[i][j] = __builtin_amdgcn_mfma_f32_16x16x32_bf16(
                        af[i], bfr[j], acc[i][j], 0, 0, 0);
        }
    }

    // Epilogue: fold relu(acc + b2) . W3 per row, atomicAdd into outacc.
    float bv[4], w3v[4];
#pragma unroll
    for (int j = 0; j < 4; j++) {
        int n = bn + (wn * 4 + j) * 16 + rl;
        bv[j] = bias[n];
        w3v[j] = W3[n];
    }
#pragma unroll
    for (int i = 0; i < 4; i++) {
#pragma unroll
        for (int r = 0; r < 4; r++) {
            float pt = 0.f;
#pragma unroll
            for (int j = 0; j < 4; j++)
                pt += fmaxf(acc[i][j][r] + bv[j], 0.f) * w3v[j];
            pt += __shfl_xor(pt, 1);
            pt += __shfl_xor(pt, 2);
            pt += __shfl_xor(pt, 4);
            pt += __shfl_xor(pt, 8);
            if (rl == 0) {
                int m = bm + (wm * 4 + i) * 16 + q * 4 + r;
                atomicAdd(&outacc[m], pt);
            }
        }
    }
}

// ---------------------------------------------------------------------------
// Sigmoid over the accumulated logits. Grid 64 x 256.
// ---------------------------------------------------------------------------
__global__ __launch_bounds__(256) void sigmoid_kernel(
    const float* __restrict__ outacc, float* __restrict__ out)
{
    int b = blockIdx.x * 256 + threadIdx.x;
    out[b] = 1.f / (1.f + __expf(-outacc[b]));
}

// ---------------------------------------------------------------------------
extern "C" void kernel_launch(void* const* d_in, const int* in_sizes, int n_in,
                              void* d_out, int out_size, void* d_ws, size_t ws_size,
                              hipStream_t stream) {
    const int*   sp    = (const int*)d_in[0];
    const float* dense = (const float*)d_in[1];
    const float* ww    = (const float*)d_in[2];
    const float* wb    = (const float*)d_in[3];
    const float* emb   = (const float*)d_in[4];
    const float* W1    = (const float*)d_in[5];
    const float* b1    = (const float*)d_in[6];
    const float* W2    = (const float*)d_in[7];
    const float* b2    = (const float*)d_in[8];
    const float* W3    = (const float*)d_in[9];
    const float* b3    = (const float*)d_in[10];
    float* out = (float*)d_out;

    char* ws = (char*)d_ws;
    float*    wide = (float*)ws;                       //     65,536 B
    uint16_t* dxp  = (uint16_t*)(ws + 65536);          //  8,388,608 B
    uint16_t* W1b  = (uint16_t*)(ws + 8454144);        //    524,288 B
    uint16_t* W2b  = (uint16_t*)(ws + 8978432);        //  2,097,152 B
    uint16_t* h1   = (uint16_t*)(ws + 11075584);       // 33,554,432 B -> 44,630,016 total

    prep_kernel<<<2752, 256, 0, stream>>>(sp, dense, emb, W1, W2, ww, wb, b3,
                                          dxp, W1b, W2b, wide);
    gemm_relu<<<(BATCH / 128) * 4, 512, 0, stream>>>(
        dxp, W1b, b1, h1, BATCH, HDIM, KPAD);
    gemm_fused<<<(BATCH / 128) * 4, 512, 0, stream>>>(
        h1, W2b, b2, W3, wide, BATCH, HDIM, HDIM);
    sigmoid_kernel<<<BATCH / 256, 256, 0, stream>>>(wide, out);
}

// Round 11
// 186.063 us; speedup vs baseline: 1.3841x; 1.2167x over previous
//
#include <hip/hip_runtime.h>
#include <stdint.h>

// ---------------------------------------------------------------------------
// WideAndDeep: B=16384, F=3, C=256, D=64, H=1024, ND=13
// deep_in = 205 padded to 224 (7 x BK=32).
// GEMM cores: R7 structure (128x256 tile, 8 waves 2m x 4n, BK=32 dbuf LDS,
// global_load_lds(16B), vmcnt(0)+__syncthreads) but with 32x32x16 MFMA:
// wave tile 64x64 = 2x2 32x32-frags, 8 MFMA/iter (vs 16), same LDS bytes.
// A/B frag: lane l <-> row l&31, k (l>>5)*8 (lane-linear dwordx4).
// C/D frag: col = lane&31, row = (reg&3) + 8*(reg>>2) + 4*(lane>>5).
// gemm_fused folds relu(acc+b2).W3 -> atomicAdd(wide). No device fences.
// ---------------------------------------------------------------------------

#define BATCH 16384
#define HDIM 1024
#define K1 224
#define DEEP_IN 205

typedef short bf16x8 __attribute__((ext_vector_type(8)));
typedef float f32x16 __attribute__((ext_vector_type(16)));
typedef uint16_t u16x8 __attribute__((ext_vector_type(8)));

__device__ __forceinline__ uint16_t f2bf(float f) {
    uint32_t x;
    __builtin_memcpy(&x, &f, 4);
    uint32_t r = (x + 0x7fffu + ((x >> 16) & 1u)) >> 16;
    return (uint16_t)r;
}

__device__ __forceinline__ void async_ld16(const uint16_t* g, uint16_t* l) {
    __builtin_amdgcn_global_load_lds(
        (const __attribute__((address_space(1))) uint32_t*)g,
        (__attribute__((address_space(3))) uint32_t*)l, 16, 0, 0);
}

// ---------------------------------------------------------------------------
// Fused prep:
//   [0, 1792)     : build deep_x [B][224] bf16 (x8 vectorized)
//   [1792, 2304)  : W2 -> bf16 (x8)
//   [2304, 2416)  : W1 -> bf16, 205 -> 224 K-pad (x8)
//   [2416, 2480)  : wide path + b3 seed (atomicAdd target for GEMM2)
// ---------------------------------------------------------------------------
__global__ __launch_bounds__(256) void prep_kernel(
    const int* __restrict__ sp, const float* __restrict__ dense,
    const float* __restrict__ emb,
    const float* __restrict__ W1, const float* __restrict__ W2,
    const float* __restrict__ ww, const float* __restrict__ wb,
    const float* __restrict__ b3,
    uint16_t* __restrict__ dx, uint16_t* __restrict__ W1b,
    uint16_t* __restrict__ W2b, float* __restrict__ wide)
{
    const int bid = blockIdx.x;
    if (bid < 1792) {                      // ---- deep_x build (16384 x 28 vec8)
        int idx = bid * 256 + threadIdx.x; // < 458752
        int b = idx / 28, c0 = (idx - b * 28) * 8;
        u16x8 o;
        if (c0 < 192) {
            int f = c0 >> 6, cc = c0 & 63;
            int s = sp[b * 3 + f];
            const float* e = emb + (size_t)(((f << 8) + s) * 64 + cc);
            float4 v0 = *(const float4*)e;
            float4 v1 = *(const float4*)(e + 4);
            o[0] = f2bf(v0.x); o[1] = f2bf(v0.y); o[2] = f2bf(v0.z); o[3] = f2bf(v0.w);
            o[4] = f2bf(v1.x); o[5] = f2bf(v1.y); o[6] = f2bf(v1.z); o[7] = f2bf(v1.w);
        } else {
#pragma unroll
            for (int t = 0; t < 8; t++) {
                int c = c0 + t;
                o[t] = (c < DEEP_IN) ? f2bf(dense[b * 13 + (c - 192)])
                                     : (uint16_t)0;
            }
        }
        *(u16x8*)(dx + (size_t)b * K1 + c0) = o;
    } else if (bid < 2304) {               // ---- W2 convert
        int k = (bid - 1792) * 256 + threadIdx.x;  // < 131072
        const float* src = W2 + (size_t)k * 8;
        float4 v0 = *(const float4*)src;
        float4 v1 = *(const float4*)(src + 4);
        u16x8 o;
        o[0] = f2bf(v0.x); o[1] = f2bf(v0.y); o[2] = f2bf(v0.z); o[3] = f2bf(v0.w);
        o[4] = f2bf(v1.x); o[5] = f2bf(v1.y); o[6] = f2bf(v1.z); o[7] = f2bf(v1.w);
        *(u16x8*)(W2b + (size_t)k * 8) = o;
    } else if (bid < 2416) {               // ---- W1 convert, 205 -> 224
        int idx = (bid - 2304) * 256 + threadIdx.x;  // < 28672
        int n = idx / 28, c0 = (idx - n * 28) * 8;
        u16x8 o;
#pragma unroll
        for (int t = 0; t < 8; t++) {
            int c = c0 + t;
            o[t] = (c < DEEP_IN) ? f2bf(W1[n * DEEP_IN + c]) : (uint16_t)0;
        }
        *(u16x8*)(W1b + (size_t)n * K1 + c0) = o;
    } else {                               // ---- wide path (+ b3 seed)
        int b = (bid - 2416) * 256 + threadIdx.x;  // < 16384
        int s0 = sp[b * 3], s1 = sp[b * 3 + 1], s2 = sp[b * 3 + 2];
        float w = wb[0] + b3[0];
        w += ww[s0] + ww[256 + s1] + ww[512 + s2];
        w += ww[768    + s0 * 3 + s1];
        w += ww[66304  + s0 * 3 + s2];
        w += ww[131840 + s1 * 3 + s2];
        w += ww[197376 + (s0 * 3 + s1) * 3 + s2];
        const float* wd = ww + 16974592;
        float acc = 0.f;
#pragma unroll
        for (int j = 0; j < 13; j++) acc += dense[b * 13 + j] * wd[j];
        wide[b] = w + acc;
    }
}

// ---------------------------------------------------------------------------
// Shared 32x32x16 GEMM core. 128x256 tile, 8 waves (wm = wave>>2 in 0..1,
// wn = wave&3 in 0..3), wave tile 64x64 = 2x2 32x32-frags (acc 4 x f32x16).
// LDS chunk = 32 rows x 16 k = 1 KB, fragment order (lane-linear x 16 B).
// A = 8 chunks (wave stages chunk (wave>>1, kc=wave&1));
// B = 16 chunks (wave stages rows wave*32..+32, both k-halves).
// BK=32 double-buffered; per-iter: 3 async_ld16/wave, 8 ds_read_b128, 8 MFMA.
// Grid (M/128)*4 = 512 blocks = 2/CU; XCD swizzle groups 4 n-sharers per XCD.
// ---------------------------------------------------------------------------
#define GEMM_CORE(A_, B_, K_)                                                  \
    const int tid = threadIdx.x;                                               \
    const int lane = tid & 63;                                                 \
    const int wave = tid >> 6;                                                 \
    const int wm = wave >> 2;                                                  \
    const int wn = wave & 3;                                                   \
    const int id = blockIdx.x;                                                 \
    const int xcd = id & 7;                                                    \
    const int slot = id >> 3;                                                  \
    const int mbX = (M >> 7) >> 3;                                             \
    const int by = xcd * mbX + (slot >> 2);                                    \
    const int bx = slot & 3;                                                   \
    const int bm = by * 128;                                                   \
    const int bn = bx * 256;                                                   \
    const int rl32 = lane & 31, q2 = lane >> 5;                                \
    f32x16 acc[2][2];                                                          \
    _Pragma("unroll") for (int i = 0; i < 2; i++)                              \
        _Pragma("unroll") for (int j = 0; j < 2; j++) acc[i][j] = (f32x16)0.f; \
    const uint16_t* aS = A_ + (size_t)(bm + (wave >> 1) * 32 + rl32) * K_      \
                            + (wave & 1) * 16 + q2 * 8;                        \
    const uint16_t* bS = B_ + (size_t)(bn + wave * 32 + rl32) * K_ + q2 * 8;   \
    const int dA = wave * 512;                                                 \
    const int dB0 = (2 * wave) * 512, dB1 = (2 * wave + 1) * 512;              \
    async_ld16(aS, &Al[0][dA]);                                                \
    async_ld16(bS, &Bl[0][dB0]);                                               \
    async_ld16(bS + 16, &Bl[0][dB1]);                                          \
    asm volatile("s_waitcnt vmcnt(0)" ::: "memory");                           \
    __syncthreads();                                                           \
    int p = 0;                                                                 \
    for (int k0 = 32; k0 < K_; k0 += 32) {                                     \
        async_ld16(aS + k0, &Al[p ^ 1][dA]);                                   \
        async_ld16(bS + k0, &Bl[p ^ 1][dB0]);                                  \
        async_ld16(bS + k0 + 16, &Bl[p ^ 1][dB1]);                             \
        bf16x8 af[2][2], bfr[2][2];                                            \
        _Pragma("unroll") for (int i = 0; i < 2; i++)                          \
            _Pragma("unroll") for (int kc = 0; kc < 2; kc++)                   \
                af[i][kc] = *(const bf16x8*)                                   \
                    &Al[p][((wm * 2 + i) * 2 + kc) * 512 + lane * 8];          \
        _Pragma("unroll") for (int j = 0; j < 2; j++)                          \
            _Pragma("unroll") for (int kc = 0; kc < 2; kc++)                   \
                bfr[j][kc] = *(const bf16x8*)                                  \
                    &Bl[p][((wn * 2 + j) * 2 + kc) * 512 + lane * 8];          \
        _Pragma("unroll") for (int i = 0; i < 2; i++)                          \
            _Pragma("unroll") for (int j = 0; j < 2; j++) {                    \
                acc[i][j] = __builtin_amdgcn_mfma_f32_32x32x16_bf16(           \
                    af[i][0], bfr[j][0], acc[i][j], 0, 0, 0);                  \
                acc[i][j] = __builtin_amdgcn_mfma_f32_32x32x16_bf16(           \
                    af[i][1], bfr[j][1], acc[i][j], 0, 0, 0);                  \
            }                                                                  \
        asm volatile("s_waitcnt vmcnt(0)" ::: "memory");                       \
        __syncthreads();                                                       \
        p ^= 1;                                                                \
    }                                                                          \
    {                                                                          \
        bf16x8 af[2][2], bfr[2][2];                                            \
        _Pragma("unroll") for (int i = 0; i < 2; i++)                          \
            _Pragma("unroll") for (int kc = 0; kc < 2; kc++)                   \
                af[i][kc] = *(const bf16x8*)                                   \
                    &Al[p][((wm * 2 + i) * 2 + kc) * 512 + lane * 8];          \
        _Pragma("unroll") for (int j = 0; j < 2; j++)                          \
            _Pragma("unroll") for (int kc = 0; kc < 2; kc++)                   \
                bfr[j][kc] = *(const bf16x8*)                                  \
                    &Bl[p][((wn * 2 + j) * 2 + kc) * 512 + lane * 8];          \
        _Pragma("unroll") for (int i = 0; i < 2; i++)                          \
            _Pragma("unroll") for (int j = 0; j < 2; j++) {                    \
                acc[i][j] = __builtin_amdgcn_mfma_f32_32x32x16_bf16(           \
                    af[i][0], bfr[j][0], acc[i][j], 0, 0, 0);                  \
                acc[i][j] = __builtin_amdgcn_mfma_f32_32x32x16_bf16(           \
                    af[i][1], bfr[j][1], acc[i][j], 0, 0, 0);                  \
            }                                                                  \
    }

// ---------------------------------------------------------------------------
// GEMM1: h1 = relu(dxp @ W1b^T + b1) bf16.
// ---------------------------------------------------------------------------
__global__ __launch_bounds__(512, 4) void gemm_relu(
    const uint16_t* __restrict__ A, const uint16_t* __restrict__ Bw,
    const float* __restrict__ bias, uint16_t* __restrict__ C,
    int M, int N, int K)
{
    __shared__ __align__(16) uint16_t Al[2][4096];   // 128 x 32 dbuf
    __shared__ __align__(16) uint16_t Bl[2][8192];   // 256 x 32 dbuf
    GEMM_CORE(A, Bw, K)
    // C/D: col = rl32, row = (r&3) + 8*(r>>2) + 4*q2
#pragma unroll
    for (int i = 0; i < 2; i++) {
#pragma unroll
        for (int j = 0; j < 2; j++) {
            int n = bn + (wn * 2 + j) * 32 + rl32;
            float bv = bias[n];
#pragma unroll
            for (int r = 0; r < 16; r++) {
                int m = bm + (wm * 2 + i) * 32 + (r & 3) + 8 * (r >> 2) + 4 * q2;
                float v = fmaxf(acc[i][j][r] + bv, 0.f);
                C[(size_t)m * N + n] = f2bf(v);
            }
        }
    }
}

// ---------------------------------------------------------------------------
// GEMM2 fused: per-row partial of relu(acc + b2) . W3 -> atomicAdd(outacc).
// ---------------------------------------------------------------------------
__global__ __launch_bounds__(512, 4) void gemm_fused(
    const uint16_t* __restrict__ A, const uint16_t* __restrict__ Bw,
    const float* __restrict__ bias, const float* __restrict__ W3,
    float* __restrict__ outacc, int M, int N, int K)
{
    __shared__ __align__(16) uint16_t Al[2][4096];
    __shared__ __align__(16) uint16_t Bl[2][8192];
    GEMM_CORE(A, Bw, K)
    float bv[2], w3v[2];
#pragma unroll
    for (int j = 0; j < 2; j++) {
        int n = bn + (wn * 2 + j) * 32 + rl32;
        bv[j] = bias[n];
        w3v[j] = W3[n];
    }
#pragma unroll
    for (int i = 0; i < 2; i++) {
#pragma unroll
        for (int r = 0; r < 16; r++) {
            float pt = 0.f;
#pragma unroll
            for (int j = 0; j < 2; j++)
                pt += fmaxf(acc[i][j][r] + bv[j], 0.f) * w3v[j];
            // reduce over the 32 rl32-lanes of this q2-half
            pt += __shfl_xor(pt, 1);
            pt += __shfl_xor(pt, 2);
            pt += __shfl_xor(pt, 4);
            pt += __shfl_xor(pt, 8);
            pt += __shfl_xor(pt, 16);
            if (rl32 == 0) {
                int m = bm + (wm * 2 + i) * 32 + (r & 3) + 8 * (r >> 2) + 4 * q2;
                atomicAdd(&outacc[m], pt);
            }
        }
    }
}

// ---------------------------------------------------------------------------
// Sigmoid over the accumulated logits. Grid 64 x 256.
// ---------------------------------------------------------------------------
__global__ __launch_bounds__(256) void sigmoid_kernel(
    const float* __restrict__ outacc, float* __restrict__ out)
{
    int b = blockIdx.x * 256 + threadIdx.x;
    out[b] = 1.f / (1.f + __expf(-outacc[b]));
}

// ---------------------------------------------------------------------------
extern "C" void kernel_launch(void* const* d_in, const int* in_sizes, int n_in,
                              void* d_out, int out_size, void* d_ws, size_t ws_size,
                              hipStream_t stream) {
    const int*   sp    = (const int*)d_in[0];
    const float* dense = (const float*)d_in[1];
    const float* ww    = (const float*)d_in[2];
    const float* wb    = (const float*)d_in[3];
    const float* emb   = (const float*)d_in[4];
    const float* W1    = (const float*)d_in[5];
    const float* b1    = (const float*)d_in[6];
    const float* W2    = (const float*)d_in[7];
    const float* b2    = (const float*)d_in[8];
    const float* W3    = (const float*)d_in[9];
    const float* b3    = (const float*)d_in[10];
    float* out = (float*)d_out;

    char* ws = (char*)d_ws;
    float*    wide = (float*)ws;                       //     65,536 B
    uint16_t* dxp  = (uint16_t*)(ws + 65536);          //  7,340,032 B (16384x224)
    uint16_t* W1b  = (uint16_t*)(ws + 7405568);        //    458,752 B (1024x224)
    uint16_t* W2b  = (uint16_t*)(ws + 7864320);        //  2,097,152 B
    uint16_t* h1   = (uint16_t*)(ws + 9961472);        // 33,554,432 B -> 43,515,904 total

    prep_kernel<<<2480, 256, 0, stream>>>(sp, dense, emb, W1, W2, ww, wb, b3,
                                          dxp, W1b, W2b, wide);
    gemm_relu<<<(BATCH / 128) * 4, 512, 0, stream>>>(
        dxp, W1b, b1, h1, BATCH, HDIM, K1);
    gemm_fused<<<(BATCH / 128) * 4, 512, 0, stream>>>(
        h1, W2b, b2, W3, wide, BATCH, HDIM, HDIM);
    sigmoid_kernel<<<BATCH / 256, 256, 0, stream>>>(wide, out);
}

// Round 12
// 181.882 us; speedup vs baseline: 1.4159x; 1.0230x over previous
//
#include <hip/hip_runtime.h>
#include <stdint.h>

// ---------------------------------------------------------------------------
// WideAndDeep: B=16384, F=3, C=256, D=64, H=1024, ND=13
// deep_in = 205 padded to 224 (7 x BK=32).
// GEMM core: R7 structure (128x256 tile, 8 waves 2m x 4n, wave tile 64x64,
// 16x16x32 MFMA, BK=32 dbuf LDS, global_load_lds(16B)) with COLUMN-PERMUTED
// B-fragments: frag j holds cols {4*rl + j}, so the epilogue packs j=0..3
// into one u16x4 (8 B) store per lane -> full 128-B row transactions for h1.
// gemm_relu's grid also carries the W2->bf16 convert and wide-path blocks
// (they only feed gemm_fused). gemm_fused folds relu(acc+b2).W3 via
// atomicAdd into wide. No device-scope fences (R8 lesson).
// ---------------------------------------------------------------------------

#define BATCH 16384
#define HDIM 1024
#define K1 224
#define DEEP_IN 205

typedef short bf16x8 __attribute__((ext_vector_type(8)));
typedef float f32x4 __attribute__((ext_vector_type(4)));
typedef uint16_t u16x8 __attribute__((ext_vector_type(8)));
typedef uint16_t u16x4 __attribute__((ext_vector_type(4)));

__device__ __forceinline__ uint16_t f2bf(float f) {
    uint32_t x;
    __builtin_memcpy(&x, &f, 4);
    uint32_t r = (x + 0x7fffu + ((x >> 16) & 1u)) >> 16;
    return (uint16_t)r;
}

__device__ __forceinline__ void async_ld16(const uint16_t* g, uint16_t* l) {
    __builtin_amdgcn_global_load_lds(
        (const __attribute__((address_space(1))) uint32_t*)g,
        (__attribute__((address_space(3))) uint32_t*)l, 16, 0, 0);
}

// ---------------------------------------------------------------------------
// prep: only what gemm_relu needs.
//   [0, 1792)     : build deep_x [B][224] bf16 (x8 vectorized)
//   [1792, 1904)  : W1 -> bf16, 205 -> 224 K-pad (x8)
// ---------------------------------------------------------------------------
__global__ __launch_bounds__(256) void prep_kernel(
    const int* __restrict__ sp, const float* __restrict__ dense,
    const float* __restrict__ emb, const float* __restrict__ W1,
    uint16_t* __restrict__ dx, uint16_t* __restrict__ W1b)
{
    const int bid = blockIdx.x;
    if (bid < 1792) {                      // ---- deep_x build (16384 x 28 vec8)
        int idx = bid * 256 + threadIdx.x; // < 458752
        int b = idx / 28, c0 = (idx - b * 28) * 8;
        u16x8 o;
        if (c0 < 192) {
            int f = c0 >> 6, cc = c0 & 63;
            int s = sp[b * 3 + f];
            const float* e = emb + (size_t)(((f << 8) + s) * 64 + cc);
            float4 v0 = *(const float4*)e;
            float4 v1 = *(const float4*)(e + 4);
            o[0] = f2bf(v0.x); o[1] = f2bf(v0.y); o[2] = f2bf(v0.z); o[3] = f2bf(v0.w);
            o[4] = f2bf(v1.x); o[5] = f2bf(v1.y); o[6] = f2bf(v1.z); o[7] = f2bf(v1.w);
        } else {
#pragma unroll
            for (int t = 0; t < 8; t++) {
                int c = c0 + t;
                o[t] = (c < DEEP_IN) ? f2bf(dense[b * 13 + (c - 192)])
                                     : (uint16_t)0;
            }
        }
        *(u16x8*)(dx + (size_t)b * K1 + c0) = o;
    } else {                               // ---- W1 convert, 205 -> 224
        int idx = (bid - 1792) * 256 + threadIdx.x;  // < 28672
        int n = idx / 28, c0 = (idx - n * 28) * 8;
        u16x8 o;
#pragma unroll
        for (int t = 0; t < 8; t++) {
            int c = c0 + t;
            o[t] = (c < DEEP_IN) ? f2bf(W1[n * DEEP_IN + c]) : (uint16_t)0;
        }
        *(u16x8*)(W1b + (size_t)n * K1 + c0) = o;
    }
}

// ---------------------------------------------------------------------------
// Shared GEMM core (R7 structure + permuted B columns).
// 128x256 tile, 8 waves (wm = wave>>2, wn = wave&3), wave tile 64x64.
// A: 8 chunks, chunk w = rows bm+w*16..+16 (natural order).
// B: 16 chunks; chunk c holds cols { bn + (c>>2)*64 + 4*rl + (c&3) } so
//    compute frag j (chunk wn*4+j) gives lane (q,rl) col bn+wn*64+4rl+j.
// BK=32 double-buffered; per-iter: 3 async_ld16/wave, 8 ds_read_b128,
// 16 MFMA 16x16x32, vmcnt(0)+__syncthreads.
// Grid (M/128)*4 = 512 blocks = 2/CU; XCD swizzle groups 4 n-sharers per XCD.
// ---------------------------------------------------------------------------
#define GEMM_CORE(A_, B_, K_)                                                  \
    const int lane = tid & 63;                                                 \
    const int wave = tid >> 6;                                                 \
    const int wm = wave >> 2;                                                  \
    const int wn = wave & 3;                                                   \
    const int xcd = id & 7;                                                    \
    const int slot = id >> 3;                                                  \
    const int mbX = (M >> 7) >> 3;                                             \
    const int by = xcd * mbX + (slot >> 2);                                    \
    const int bx = slot & 3;                                                   \
    const int bm = by * 128;                                                   \
    const int bn = bx * 256;                                                   \
    const int rl = lane & 15, q = lane >> 4;                                   \
    f32x4 acc[4][4];                                                           \
    _Pragma("unroll") for (int i = 0; i < 4; i++)                              \
        _Pragma("unroll") for (int j = 0; j < 4; j++) acc[i][j] = (f32x4)0.f;  \
    const int c0 = 2 * wave, c1 = 2 * wave + 1;                                \
    const uint16_t* aS = A_ + (size_t)(bm + wave * 16 + rl) * K_ + q * 8;      \
    const uint16_t* bS0 = B_ + (size_t)(bn + (c0 >> 2) * 64 + 4 * rl + (c0 & 3)) * K_ + q * 8; \
    const uint16_t* bS1 = B_ + (size_t)(bn + (c1 >> 2) * 64 + 4 * rl + (c1 & 3)) * K_ + q * 8; \
    const int dA = wave * 512, dB0 = c0 * 512, dB1 = c1 * 512;                 \
    async_ld16(aS, &Al[0][dA]);                                                \
    async_ld16(bS0, &Bl[0][dB0]);                                              \
    async_ld16(bS1, &Bl[0][dB1]);                                              \
    asm volatile("s_waitcnt vmcnt(0)" ::: "memory");                           \
    __syncthreads();                                                           \
    int p = 0;                                                                 \
    for (int k0 = 32; k0 < K_; k0 += 32) {                                     \
        async_ld16(aS + k0, &Al[p ^ 1][dA]);                                   \
        async_ld16(bS0 + k0, &Bl[p ^ 1][dB0]);                                 \
        async_ld16(bS1 + k0, &Bl[p ^ 1][dB1]);                                 \
        bf16x8 af[4], bfr[4];                                                  \
        _Pragma("unroll") for (int i = 0; i < 4; i++)                          \
            af[i] = *(const bf16x8*)&Al[p][(wm * 4 + i) * 512 + lane * 8];     \
        _Pragma("unroll") for (int j = 0; j < 4; j++)                          \
            bfr[j] = *(const bf16x8*)&Bl[p][(wn * 4 + j) * 512 + lane * 8];    \
        _Pragma("unroll") for (int i = 0; i < 4; i++)                          \
            _Pragma("unroll") for (int j = 0; j < 4; j++)                      \
                acc[i][j] = __builtin_amdgcn_mfma_f32_16x16x32_bf16(           \
                    af[i], bfr[j], acc[i][j], 0, 0, 0);                        \
        asm volatile("s_waitcnt vmcnt(0)" ::: "memory");                       \
        __syncthreads();                                                       \
        p ^= 1;                                                                \
    }                                                                          \
    {                                                                          \
        bf16x8 af[4], bfr[4];                                                  \
        _Pragma("unroll") for (int i = 0; i < 4; i++)                          \
            af[i] = *(const bf16x8*)&Al[p][(wm * 4 + i) * 512 + lane * 8];     \
        _Pragma("unroll") for (int j = 0; j < 4; j++)                          \
            bfr[j] = *(const bf16x8*)&Bl[p][(wn * 4 + j) * 512 + lane * 8];    \
        _Pragma("unroll") for (int i = 0; i < 4; i++)                          \
            _Pragma("unroll") for (int j = 0; j < 4; j++)                      \
                acc[i][j] = __builtin_amdgcn_mfma_f32_16x16x32_bf16(           \
                    af[i], bfr[j], acc[i][j], 0, 0, 0);                        \
    }

// ---------------------------------------------------------------------------
// gemm_relu: [0,512) h1 = relu(dxp @ W1b^T + b1), u16x4 packed row stores;
//            [512,768) W2 -> bf16 convert; [768,800) wide path + b3 seed.
// ---------------------------------------------------------------------------
__global__ __launch_bounds__(512, 4) void gemm_relu(
    const uint16_t* __restrict__ A, const uint16_t* __restrict__ Bw,
    const float* __restrict__ bias, uint16_t* __restrict__ C,
    const float* __restrict__ W2, uint16_t* __restrict__ W2b,
    const int* __restrict__ sp, const float* __restrict__ dense,
    const float* __restrict__ ww, const float* __restrict__ wb,
    const float* __restrict__ b3, float* __restrict__ wide,
    int M, int N, int K)
{
    const int id = blockIdx.x;
    const int tid = threadIdx.x;

    if (id >= 512) {
        if (id < 768) {                    // ---- W2 convert (x8)
            int k = (id - 512) * 512 + tid;    // < 131072
            const float* src = W2 + (size_t)k * 8;
            float4 v0 = *(const float4*)src;
            float4 v1 = *(const float4*)(src + 4);
            u16x8 o;
            o[0] = f2bf(v0.x); o[1] = f2bf(v0.y); o[2] = f2bf(v0.z); o[3] = f2bf(v0.w);
            o[4] = f2bf(v1.x); o[5] = f2bf(v1.y); o[6] = f2bf(v1.z); o[7] = f2bf(v1.w);
            *(u16x8*)(W2b + (size_t)k * 8) = o;
        } else {                           // ---- wide path (+ b3 seed)
            int b = (id - 768) * 512 + tid;    // < 16384
            int s0 = sp[b * 3], s1 = sp[b * 3 + 1], s2 = sp[b * 3 + 2];
            float w = wb[0] + b3[0];
            w += ww[s0] + ww[256 + s1] + ww[512 + s2];
            w += ww[768    + s0 * 3 + s1];
            w += ww[66304  + s0 * 3 + s2];
            w += ww[131840 + s1 * 3 + s2];
            w += ww[197376 + (s0 * 3 + s1) * 3 + s2];
            const float* wd = ww + 16974592;
            float acc2 = 0.f;
#pragma unroll
            for (int j = 0; j < 13; j++) acc2 += dense[b * 13 + j] * wd[j];
            wide[b] = w + acc2;
        }
        return;
    }

    __shared__ __align__(16) uint16_t Al[2][4096];   // 128 x 32 dbuf
    __shared__ __align__(16) uint16_t Bl[2][8192];   // 256 x 32 dbuf
    GEMM_CORE(A, Bw, K)

    // Epilogue: lane (q,rl) owns cols bn+wn*64+4rl+j (j=0..3) of rows
    // m = bm+wm*64+i*16+q*4+r -> one u16x4 (8 B) store per (i,r).
    float bv[4];
#pragma unroll
    for (int j = 0; j < 4; j++) bv[j] = bias[bn + wn * 64 + 4 * rl + j];
#pragma unroll
    for (int i = 0; i < 4; i++) {
#pragma unroll
        for (int r = 0; r < 4; r++) {
            int m = bm + wm * 64 + i * 16 + q * 4 + r;
            u16x4 o;
#pragma unroll
            for (int j = 0; j < 4; j++)
                o[j] = f2bf(fmaxf(acc[i][j][r] + bv[j], 0.f));
            *(u16x4*)&C[(size_t)m * N + bn + wn * 64 + 4 * rl] = o;
        }
    }
}

// ---------------------------------------------------------------------------
// gemm_fused: per-row partial of relu(acc + b2) . W3 -> atomicAdd(outacc).
// (n-permutation is irrelevant to the sum.)
// ---------------------------------------------------------------------------
__global__ __launch_bounds__(512, 4) void gemm_fused(
    const uint16_t* __restrict__ A, const uint16_t* __restrict__ Bw,
    const float* __restrict__ bias, const float* __restrict__ W3,
    float* __restrict__ outacc, int M, int N, int K)
{
    const int id = blockIdx.x;
    const int tid = threadIdx.x;
    __shared__ __align__(16) uint16_t Al[2][4096];
    __shared__ __align__(16) uint16_t Bl[2][8192];
    GEMM_CORE(A, Bw, K)

    float bv[4], w3v[4];
#pragma unroll
    for (int j = 0; j < 4; j++) {
        int n = bn + wn * 64 + 4 * rl + j;
        bv[j] = bias[n];
        w3v[j] = W3[n];
    }
#pragma unroll
    for (int i = 0; i < 4; i++) {
#pragma unroll
        for (int r = 0; r < 4; r++) {
            float pt = 0.f;
#pragma unroll
            for (int j = 0; j < 4; j++)
                pt += fmaxf(acc[i][j][r] + bv[j], 0.f) * w3v[j];
            pt += __shfl_xor(pt, 1);
            pt += __shfl_xor(pt, 2);
            pt += __shfl_xor(pt, 4);
            pt += __shfl_xor(pt, 8);
            if (rl == 0) {
                int m = bm + wm * 64 + i * 16 + q * 4 + r;
                atomicAdd(&outacc[m], pt);
            }
        }
    }
}

// ---------------------------------------------------------------------------
// Sigmoid over the accumulated logits. Grid 64 x 256.
// ---------------------------------------------------------------------------
__global__ __launch_bounds__(256) void sigmoid_kernel(
    const float* __restrict__ outacc, float* __restrict__ out)
{
    int b = blockIdx.x * 256 + threadIdx.x;
    out[b] = 1.f / (1.f + __expf(-outacc[b]));
}

// ---------------------------------------------------------------------------
extern "C" void kernel_launch(void* const* d_in, const int* in_sizes, int n_in,
                              void* d_out, int out_size, void* d_ws, size_t ws_size,
                              hipStream_t stream) {
    const int*   sp    = (const int*)d_in[0];
    const float* dense = (const float*)d_in[1];
    const float* ww    = (const float*)d_in[2];
    const float* wb    = (const float*)d_in[3];
    const float* emb   = (const float*)d_in[4];
    const float* W1    = (const float*)d_in[5];
    const float* b1    = (const float*)d_in[6];
    const float* W2    = (const float*)d_in[7];
    const float* b2    = (const float*)d_in[8];
    const float* W3    = (const float*)d_in[9];
    const float* b3    = (const float*)d_in[10];
    float* out = (float*)d_out;

    char* ws = (char*)d_ws;
    float*    wide = (float*)ws;                       //     65,536 B
    uint16_t* dxp  = (uint16_t*)(ws + 65536);          //  7,340,032 B (16384x224)
    uint16_t* W1b  = (uint16_t*)(ws + 7405568);        //    458,752 B (1024x224)
    uint16_t* W2b  = (uint16_t*)(ws + 7864320);        //  2,097,152 B
    uint16_t* h1   = (uint16_t*)(ws + 9961472);        // 33,554,432 B -> 43,515,904 total

    prep_kernel<<<1904, 256, 0, stream>>>(sp, dense, emb, W1, dxp, W1b);
    gemm_relu<<<800, 512, 0, stream>>>(
        dxp, W1b, b1, h1, W2, W2b, sp, dense, ww, wb, b3, wide,
        BATCH, HDIM, K1);
    gemm_fused<<<(BATCH / 128) * 4, 512, 0, stream>>>(
        h1, W2b, b2, W3, wide, BATCH, HDIM, HDIM);
    sigmoid_kernel<<<BATCH / 256, 256, 0, stream>>>(wide, out);
}